// Round 5
// baseline (1025.636 us; speedup 1.0000x reference)
//
#include <hip/hip_runtime.h>
#include <hip/hip_bf16.h>

// FCGF point attention head — MFMA (bf16) implementation.
// x [N=524288, C=32] -> h = relu(BN(x@w1^T+b1)) [N,128]
//                    -> att = relu(BN(h@w2^T+b2)) [N,512]
// per-segment (L=32768, B=16): pooled[b] = att_b^T @ x_b / L ; gp[b] = sum att
// res = L2norm_rows(BN_over_B(pooled.flat @ wf^T + bf))
// outputs concat: res (4096) | gp (8192) | lengths (16)
//
// BN stats via moment trick: var(w.v) = w E[vv^T] w^T - (w E[v])^2 using
// S1 = x^T x (f32) and G = h^T h (bf16 MFMA). G symmetric ->
// q_k = w2[k] G w2[k]^T parallelizes as one block per channel.
// R4: bias-in-MFMA-accumulator, register prefetch of next chunk's x,
//     kB hT race fix (barrier), two-stage partial reduces.

#define SEGLEN 32768
#define BN_EPS 1e-5f
#define INV_N (1.0f/524288.0f)
#define INV_L (1.0f/32768.0f)

// ---- ws layout (float units) ----
#define WS_S1P   0                       // 512*1056
#define WS_S1    540672                  // 1056
#define WS_W1F   541728                  // 2048 f = 4096 bf16  [128][32]
#define WS_B1P   543776                  // 128
#define WS_GP    543904                  // 256*16512
#define WS_G     4770976                 // 16512
#define WS_W2F   4787488                 // 32768 f = 65536 bf16 [512][128]
#define WS_B2P   4820256                 // 512
#define WS_PP    4820768                 // 256*16896 pooled partials (+gp); also reduce tmp
#define WS_PR    9146144                 // 16*16384 pooled reduced
#define WS_TP    9408288                 // 16*16*256 fc partials
// end 9473824 floats = 37.9 MB

typedef __attribute__((ext_vector_type(8))) short bf16x8;  // 8 bf16 (4 VGPR)
typedef __attribute__((ext_vector_type(4))) float f32x4;   // C/D frag
#define MFMA(a,b,c) __builtin_amdgcn_mfma_f32_16x16x32_bf16(a,b,c,0,0,0)

__device__ __forceinline__ unsigned short f2b(float f) {
    unsigned u = __builtin_bit_cast(unsigned, f);
    return (unsigned short)((u + 0x7FFFu + ((u >> 16) & 1u)) >> 16);
}
__device__ __forceinline__ unsigned pk2(float lo, float hi) {
    return (unsigned)f2b(lo) | ((unsigned)f2b(hi) << 16);
}

// ---------------- K1: S1 = x^T x partials, sx partials (f32) ----------------
__global__ __launch_bounds__(256) void k1_stats_x(const float* __restrict__ x,
                                                  float* __restrict__ part) {
    __shared__ float xs[64 * 36];
    const int tid = threadIdx.x;
    const int blk = blockIdx.x;            // 512 blocks, 1024 pts each
    const long base = (long)blk * 1024;
    float acc0 = 0.f, acc1 = 0.f, acc2 = 0.f, acc3 = 0.f;
    float sxa = 0.f;
    const int i0 = (tid * 4) >> 5;
    const int j0 = (tid * 4) & 31;
    const int sp0 = tid >> 3, sc4 = (tid & 7) * 4;   // stage coords (2 rows/thread)
    float4 st0 = *(const float4*)&x[(base + sp0) * 32 + sc4];
    float4 st1 = *(const float4*)&x[(base + sp0 + 32) * 32 + sc4];
    for (int t0 = 0; t0 < 1024; t0 += 64) {
        __syncthreads();
        *(float4*)&xs[sp0 * 36 + sc4] = st0;
        *(float4*)&xs[(sp0 + 32) * 36 + sc4] = st1;
        if (t0 < 960) {   // prefetch next tile
            st0 = *(const float4*)&x[(base + t0 + 64 + sp0) * 32 + sc4];
            st1 = *(const float4*)&x[(base + t0 + 64 + sp0 + 32) * 32 + sc4];
        }
        __syncthreads();
        #pragma unroll 8
        for (int p = 0; p < 64; p++) {
            float xi = xs[p * 36 + i0];
            float4 xj = *(float4*)&xs[p * 36 + j0];
            acc0 += xi * xj.x; acc1 += xi * xj.y;
            acc2 += xi * xj.z; acc3 += xi * xj.w;
        }
        if (tid < 32) {
            #pragma unroll 8
            for (int p = 0; p < 64; p++) sxa += xs[p * 36 + tid];
        }
    }
    float* dst = part + (long)blk * 1056;
    *(float4*)&dst[tid * 4] = make_float4(acc0, acc1, acc2, acc3);
    if (tid < 32) dst[1024 + tid] = sxa;
}

// ---------------- two-stage partial reduce ----------------
__global__ void k_reduceA(const float* __restrict__ in, float* __restrict__ out,
                          int npp, int nentries) {
    // block (x,y): entries slice x, part-group y of size npp
    int e = blockIdx.x * 256 + threadIdx.x;
    if (e >= nentries) return;
    const float* src = in + (long)blockIdx.y * npp * nentries;
    float s = 0.f;
    #pragma unroll 8
    for (int p = 0; p < npp; p++) s += src[(long)p * nentries + e];
    out[(long)blockIdx.y * nentries + e] = s;
}

__global__ void k_reduce(const float* __restrict__ in, float* __restrict__ out,
                         int nparts, int nentries) {
    int e = blockIdx.x * 256 + threadIdx.x;
    if (e >= nentries) return;
    float s = 0.f;
    #pragma unroll 8
    for (int p = 0; p < nparts; p++) s += in[(long)p * nentries + e];
    out[e] = s;
}

// ---------------- K2: fold BN1 -> w1f (bf16) / b1p ----------------
__global__ __launch_bounds__(128) void k2_fold1(const float* __restrict__ S1,
                                                const float* __restrict__ w1,
                                                const float* __restrict__ b1,
                                                const float* __restrict__ g1,
                                                const float* __restrict__ be1,
                                                unsigned short* __restrict__ w1f,
                                                float* __restrict__ b1p) {
    __shared__ float s1[1056];
    const int k = threadIdx.x;
    for (int q = k; q < 1056; q += 128) s1[q] = S1[q];
    __syncthreads();
    float w[32];
    #pragma unroll
    for (int c = 0; c < 32; c++) w[c] = w1[k * 32 + c];
    float s = 0.f;
    #pragma unroll
    for (int c = 0; c < 32; c++) s += w[c] * s1[1024 + c];
    s *= INV_N;
    float q = 0.f;
    for (int i = 0; i < 32; i++) {
        float t = 0.f;
        #pragma unroll
        for (int j = 0; j < 32; j++) t += s1[i * 32 + j] * w[j];
        q += w[i] * t;
    }
    q *= INV_N;
    float var = q - s * s;
    float mu = s + b1[k];
    float a = g1[k] * rsqrtf(var + BN_EPS);
    #pragma unroll
    for (int c = 0; c < 32; c++) w1f[k * 32 + c] = f2b(a * w[c]);
    b1p[k] = a * (b1[k] - mu) + be1[k];
}

// ---------------- KB: h (MFMA) -> G = h^T h partials + sh ----------------
__global__ __launch_bounds__(512, 4) void kB_stats(const float* __restrict__ x,
                                                   const unsigned short* __restrict__ w1f,
                                                   const float* __restrict__ b1p,
                                                   float* __restrict__ gpart) {
    __shared__ unsigned short xsb[64 * 40];   // bf16 x tile [pt][40pad]
    __shared__ unsigned short hT[128 * 72];   // bf16 h^T [ch][72pad pts]
    __shared__ float shred[8 * 64];
    const int tid = threadIdx.x;
    const int wave = tid >> 6, lane = tid & 63;
    const int l15 = lane & 15, lg = lane >> 4;
    const int ptile = wave & 3, chalf = wave >> 2;
    const long base = (long)blockIdx.x * 2048;
    const f32x4 zero4 = {0.f, 0.f, 0.f, 0.f};
    bf16x8 wb1[4];
    f32x4 binit1[4];
    #pragma unroll
    for (int c = 0; c < 4; c++) {
        int ch = chalf * 64 + c * 16 + l15;
        wb1[c] = *(const bf16x8*)&w1f[ch * 32 + lg * 8];
        float b = b1p[ch];
        binit1[c] = (f32x4){b, b, b, b};
    }
    f32x4 gacc[8];
    #pragma unroll
    for (int t = 0; t < 8; t++) gacc[t] = zero4;
    float shacc[4] = {0.f, 0.f, 0.f, 0.f};
    const int sp = tid >> 3, sc4 = (tid & 7) * 4;
    float4 xsg = *(const float4*)&x[(base + sp) * 32 + sc4];
    for (int ck = 0; ck < 32; ck++) {
        __syncthreads();
        *(uint2*)&xsb[sp * 40 + sc4] =
            make_uint2(pk2(xsg.x, xsg.y), pk2(xsg.z, xsg.w));
        if (ck < 31)
            xsg = *(const float4*)&x[(base + (ck + 1) * 64 + sp) * 32 + sc4];
        __syncthreads();
        // h = relu(x @ w1f^T + b1p), write hT[ch][pt]
        bf16x8 xa = *(const bf16x8*)&xsb[(ptile * 16 + l15) * 40 + lg * 8];
        #pragma unroll
        for (int c = 0; c < 4; c++) {
            f32x4 hf = MFMA(xa, wb1[c], binit1[c]);
            float v0 = fmaxf(hf[0], 0.f);
            float v1 = fmaxf(hf[1], 0.f);
            float v2 = fmaxf(hf[2], 0.f);
            float v3 = fmaxf(hf[3], 0.f);
            shacc[c] += v0 + v1 + v2 + v3;
            int ch = chalf * 64 + c * 16 + l15;
            *(uint2*)&hT[ch * 72 + ptile * 16 + lg * 4] =
                make_uint2(pk2(v0, v1), pk2(v2, v3));
        }
        __syncthreads();   // hT ready across waves (race fix)
        // G += hT-tile outer product (wave owns row-tile `wave`)
        #pragma unroll
        for (int ks = 0; ks < 2; ks++) {
            bf16x8 ga = *(const bf16x8*)&hT[(wave * 16 + l15) * 72 + ks * 32 + lg * 8];
            #pragma unroll
            for (int ct = 0; ct < 8; ct++) {
                bf16x8 gb = *(const bf16x8*)&hT[(ct * 16 + l15) * 72 + ks * 32 + lg * 8];
                gacc[ct] = MFMA(ga, gb, gacc[ct]);
            }
        }
    }
    float* dst = gpart + (long)blockIdx.x * 16512;
    #pragma unroll
    for (int ct = 0; ct < 8; ct++) {
        #pragma unroll
        for (int r = 0; r < 4; r++)
            dst[(wave * 16 + lg * 4 + r) * 128 + ct * 16 + l15] = gacc[ct][r];
    }
    #pragma unroll
    for (int c = 0; c < 4; c++) {
        float v = shacc[c];
        v += __shfl_xor(v, 16);
        v += __shfl_xor(v, 32);
        if (lane < 16) shred[wave * 64 + c * 16 + lane] = v;
    }
    __syncthreads();
    if (tid < 128) {
        float s = 0.f;
        #pragma unroll
        for (int pt = 0; pt < 4; pt++)
            s += shred[((tid >> 6) * 4 + pt) * 64 + (tid & 63)];
        dst[16384 + tid] = s;
    }
}

// ---------------- K4: fold BN2 -> w2f (bf16 [512][128]) / b2p ----------------
__global__ __launch_bounds__(128) void k4_fold2(const float* __restrict__ G,
                                                const float* __restrict__ w2,
                                                const float* __restrict__ b2,
                                                const float* __restrict__ g2,
                                                const float* __restrict__ be2,
                                                unsigned short* __restrict__ w2f,
                                                float* __restrict__ b2p) {
    __shared__ float wsh[128];
    __shared__ float red[4];
    const int i = threadIdx.x;
    const int k = blockIdx.x;              // 512 blocks
    const float wi = w2[(long)k * 128 + i];
    wsh[i] = wi;
    __syncthreads();
    float t = 0.f;
    const float* grow = &G[i * 128];
    #pragma unroll 16
    for (int j = 0; j < 128; j++) t += grow[j] * wsh[j];
    float qp = wi * t;                     // partial of w^T G w
    float sp = wi * G[16384 + i];          // partial of w . sh
    #pragma unroll
    for (int o = 1; o < 64; o <<= 1) {
        qp += __shfl_xor(qp, o);
        sp += __shfl_xor(sp, o);
    }
    if ((i & 63) == 0) {
        red[(i >> 6) * 2 + 0] = qp;
        red[(i >> 6) * 2 + 1] = sp;
    }
    __syncthreads();
    const float q = (red[0] + red[2]) * INV_N;
    const float s = (red[1] + red[3]) * INV_N;
    const float var = q - s * s;
    const float a = g2[k] * rsqrtf(var + BN_EPS);
    w2f[(long)k * 128 + i] = f2b(a * wi);
    if (i == 0) b2p[k] = -a * s + be2[k];
}

// ---------------- KD: main fused pass (all-MFMA) ----------------
__global__ __launch_bounds__(512, 4) void kD_main(const float* __restrict__ x,
        const unsigned short* __restrict__ w1f, const float* __restrict__ b1p,
        const unsigned short* __restrict__ w2f, const float* __restrict__ b2p,
        float* __restrict__ ppart) {
    __shared__ unsigned short xT[32 * 72];      // bf16 x^T [c][72pad pts]
    __shared__ unsigned short hs[64 * 136];     // bf16 h [pt][136pad ch]
    __shared__ unsigned short attT[8][64 * 40]; // per-wave att^T [chL][40pad pts(32)]
    const int tid = threadIdx.x;
    const int wave = tid >> 6, lane = tid & 63;
    const int l15 = lane & 15, lg = lane >> 4;
    const int ptile = wave & 3, chalf = wave >> 2;
    const int kb = wave * 64;                   // att channel block
    const long base = (long)blockIdx.x * 2048;
    const f32x4 zero4 = {0.f, 0.f, 0.f, 0.f};
    bf16x8 wb1[4];
    f32x4 binit1[4];
    #pragma unroll
    for (int c = 0; c < 4; c++) {
        int ch = chalf * 64 + c * 16 + l15;
        wb1[c] = *(const bf16x8*)&w1f[ch * 32 + lg * 8];
        float b = b1p[ch];
        binit1[c] = (f32x4){b, b, b, b};
    }
    bf16x8 wb2[4][4];
    f32x4 binit2[4];
    #pragma unroll
    for (int c = 0; c < 4; c++) {
        int ch = kb + c * 16 + l15;
        #pragma unroll
        for (int ks = 0; ks < 4; ks++)
            wb2[c][ks] = *(const bf16x8*)&w2f[(long)ch * 128 + ks * 32 + lg * 8];
        float b = b2p[ch];
        binit2[c] = (f32x4){b, b, b, b};
    }
    f32x4 pacc[4][2];
    #pragma unroll
    for (int t = 0; t < 4; t++) { pacc[t][0] = zero4; pacc[t][1] = zero4; }
    float gpacc[4] = {0.f, 0.f, 0.f, 0.f};
    const int sp = tid >> 3, sc4 = (tid & 7) * 4;   // xT stage coords
    const int hpt = ptile * 16 + l15;               // h A-frag point
    float4 xsg, xh0, xh1;
    xsg = *(const float4*)&x[(base + sp) * 32 + sc4];
    {
        const float* r = &x[(base + hpt) * 32 + lg * 8];
        xh0 = *(const float4*)&r[0];
        xh1 = *(const float4*)&r[4];
    }
    for (int ck = 0; ck < 32; ck++) {
        __syncthreads();
        {   // stage x^T (bf16) from prefetched regs
            xT[(sc4 + 0) * 72 + sp] = f2b(xsg.x);
            xT[(sc4 + 1) * 72 + sp] = f2b(xsg.y);
            xT[(sc4 + 2) * 72 + sp] = f2b(xsg.z);
            xT[(sc4 + 3) * 72 + sp] = f2b(xsg.w);
        }
        {   // h tiles from prefetched regs
            bf16x8 xa;
            ((unsigned*)&xa)[0] = pk2(xh0.x, xh0.y);
            ((unsigned*)&xa)[1] = pk2(xh0.z, xh0.w);
            ((unsigned*)&xa)[2] = pk2(xh1.x, xh1.y);
            ((unsigned*)&xa)[3] = pk2(xh1.z, xh1.w);
            #pragma unroll
            for (int c = 0; c < 4; c++) {
                f32x4 hf = MFMA(xa, wb1[c], binit1[c]);
                int chh = chalf * 64 + c * 16 + l15;
                #pragma unroll
                for (int r = 0; r < 4; r++)
                    hs[(ptile * 16 + lg * 4 + r) * 136 + chh] =
                        f2b(fmaxf(hf[r], 0.f));
            }
        }
        if (ck < 31) {   // prefetch next chunk
            long nb = base + (ck + 1) * 64;
            xsg = *(const float4*)&x[(nb + sp) * 32 + sc4];
            const float* r = &x[(nb + hpt) * 32 + lg * 8];
            xh0 = *(const float4*)&r[0];
            xh1 = *(const float4*)&r[4];
        }
        __syncthreads();
        #pragma unroll
        for (int ph = 0; ph < 2; ph++) {       // two 32-pt halves
            f32x4 zt[2][4];
            #pragma unroll
            for (int r = 0; r < 2; r++) {
                zt[r][0] = binit2[0]; zt[r][1] = binit2[1];
                zt[r][2] = binit2[2]; zt[r][3] = binit2[3];
            }
            #pragma unroll
            for (int ks = 0; ks < 4; ks++) {
                bf16x8 ha[2];
                #pragma unroll
                for (int r = 0; r < 2; r++)
                    ha[r] = *(const bf16x8*)&hs[(ph * 32 + r * 16 + l15) * 136 + ks * 32 + lg * 8];
                #pragma unroll
                for (int r = 0; r < 2; r++)
                    #pragma unroll
                    for (int c = 0; c < 4; c++)
                        zt[r][c] = MFMA(ha[r], wb2[c][ks], zt[r][c]);
            }
            // relu + gp + att^T bounce (per-wave LDS region, no barrier)
            #pragma unroll
            for (int r = 0; r < 2; r++) {
                #pragma unroll
                for (int c = 0; c < 4; c++) {
                    float a0 = fmaxf(zt[r][c][0], 0.f);
                    float a1 = fmaxf(zt[r][c][1], 0.f);
                    float a2 = fmaxf(zt[r][c][2], 0.f);
                    float a3 = fmaxf(zt[r][c][3], 0.f);
                    gpacc[c] += a0 + a1 + a2 + a3;
                    *(uint2*)&attT[wave][(c * 16 + l15) * 40 + r * 16 + lg * 4] =
                        make_uint2(pk2(a0, a1), pk2(a2, a3));
                }
            }
            // pooled += att^T @ x  (K = this 32-pt half)
            bf16x8 xb[2];
            #pragma unroll
            for (int u = 0; u < 2; u++)
                xb[u] = *(const bf16x8*)&xT[(u * 16 + l15) * 72 + ph * 32 + lg * 8];
            #pragma unroll
            for (int t = 0; t < 4; t++) {
                bf16x8 aa = *(const bf16x8*)&attT[wave][(t * 16 + l15) * 40 + lg * 8];
                #pragma unroll
                for (int u = 0; u < 2; u++)
                    pacc[t][u] = MFMA(aa, xb[u], pacc[t][u]);
            }
        }
    }
    float* dst = ppart + (long)blockIdx.x * 16896;
    #pragma unroll
    for (int t = 0; t < 4; t++)
        #pragma unroll
        for (int u = 0; u < 2; u++)
            #pragma unroll
            for (int r = 0; r < 4; r++)
                dst[(kb + t * 16 + lg * 4 + r) * 32 + u * 16 + l15] = pacc[t][u][r];
    #pragma unroll
    for (int c = 0; c < 4; c++) {
        float v = gpacc[c];
        v += __shfl_xor(v, 16);
        v += __shfl_xor(v, 32);
        if (lane < 16) dst[16384 + kb + c * 16 + lane] = v;
    }
}

// ---------------- K5b: reduce pooled partials, emit gp ----------------
__global__ void k5b_reduce_pool(const float* __restrict__ part,
                                float* __restrict__ pooled_red,
                                float* __restrict__ out) {
    const int seg = blockIdx.y;
    const int e = blockIdx.x * 256 + threadIdx.x;
    if (e >= 16896) return;
    float s = 0.f;
    #pragma unroll
    for (int p = 0; p < 16; p++)
        s += part[(long)(seg * 16 + p) * 16896 + e];
    if (e < 16384) pooled_red[seg * 16384 + e] = s;
    else out[4096 + seg * 512 + (e - 16384)] = s;   // gp
}

// ---------------- K6a: fc partials over k-blocks ----------------
__global__ __launch_bounds__(256) void k6a_fc(const float* __restrict__ pr,
                                              const float* __restrict__ wf,
                                              float* __restrict__ tpart) {
    const int kbk = blockIdx.x, jb = blockIdx.y;
    const int j = jb * 16 + (threadIdx.x >> 4), b = threadIdx.x & 15;
    const float4* wrow = (const float4*)&wf[(long)j * 16384 + kbk * 1024];
    const float4* prow = (const float4*)&pr[(long)b * 16384 + kbk * 1024];
    float acc = 0.f;
    #pragma unroll 8
    for (int u = 0; u < 256; u++) {
        float4 w = wrow[u], p = prow[u];
        acc += w.x * p.x + w.y * p.y + w.z * p.z + w.w * p.w;
    }
    tpart[(kbk * 16 + b) * 256 + j] = acc;
}

// ---------------- K6b: reduce fc + BN over B + L2 normalize ----------------
__global__ __launch_bounds__(256) void k6b_final(const float* __restrict__ tpart,
                                                 const float* __restrict__ bf_,
                                                 const float* __restrict__ gf,
                                                 const float* __restrict__ bef,
                                                 float* __restrict__ out) {
    __shared__ float ts[16 * 256];
    __shared__ float rs[16 * 256];
    __shared__ float nrm[16];
    const int tid = threadIdx.x;
    for (int b = 0; b < 16; b++) {
        float s = 0.f;
        #pragma unroll
        for (int kbk = 0; kbk < 16; kbk++) s += tpart[(kbk * 16 + b) * 256 + tid];
        ts[b * 256 + tid] = s * INV_L + bf_[tid];
    }
    __syncthreads();
    float mu = 0.f;
    #pragma unroll
    for (int b = 0; b < 16; b++) mu += ts[b * 256 + tid];
    mu *= (1.f / 16.f);
    float var = 0.f;
    #pragma unroll
    for (int b = 0; b < 16; b++) {
        float d = ts[b * 256 + tid] - mu;
        var += d * d;
    }
    var *= (1.f / 16.f);
    float a = gf[tid] * rsqrtf(var + BN_EPS);
    #pragma unroll
    for (int b = 0; b < 16; b++)
        rs[b * 256 + tid] = (ts[b * 256 + tid] - mu) * a + bef[tid];
    __syncthreads();
    {   // parallel L2-norm: 16 lanes per segment
        const int pb = tid >> 4, l16 = tid & 15;
        float s = 0.f;
        #pragma unroll
        for (int j = 0; j < 16; j++) {
            float v = rs[pb * 256 + l16 + j * 16];
            s += v * v;
        }
        s += __shfl_xor(s, 1); s += __shfl_xor(s, 2);
        s += __shfl_xor(s, 4); s += __shfl_xor(s, 8);
        if (l16 == 0) nrm[pb] = fmaxf(sqrtf(s), 1e-12f);
    }
    __syncthreads();
    #pragma unroll
    for (int b = 0; b < 16; b++)
        out[b * 256 + tid] = rs[b * 256 + tid] / nrm[b];
    if (tid < 16) out[12288 + tid] = 32768.0f;   // lengths
}

extern "C" void kernel_launch(void* const* d_in, const int* in_sizes, int n_in,
                              void* d_out, int out_size, void* d_ws, size_t ws_size,
                              hipStream_t stream) {
    (void)in_sizes; (void)n_in; (void)out_size; (void)ws_size;
    const float* x   = (const float*)d_in[0];
    const float* w1  = (const float*)d_in[1];
    const float* b1  = (const float*)d_in[2];
    const float* g1  = (const float*)d_in[3];
    const float* be1 = (const float*)d_in[4];
    const float* w2  = (const float*)d_in[5];
    const float* b2  = (const float*)d_in[6];
    const float* g2  = (const float*)d_in[7];
    const float* be2 = (const float*)d_in[8];
    const float* wf  = (const float*)d_in[9];
    const float* bf  = (const float*)d_in[10];
    const float* gf  = (const float*)d_in[11];
    const float* bef = (const float*)d_in[12];
    float* out = (float*)d_out;
    float* ws = (float*)d_ws;
    unsigned short* w1f = (unsigned short*)(ws + WS_W1F);
    unsigned short* w2f = (unsigned short*)(ws + WS_W2F);

    k1_stats_x<<<512, 256, 0, stream>>>(x, ws + WS_S1P);
    k_reduceA<<<dim3(5, 8), 256, 0, stream>>>(ws + WS_S1P, ws + WS_PP, 64, 1056);
    k_reduce<<<5, 256, 0, stream>>>(ws + WS_PP, ws + WS_S1, 8, 1056);
    k2_fold1<<<1, 128, 0, stream>>>(ws + WS_S1, w1, b1, g1, be1, w1f, ws + WS_B1P);
    kB_stats<<<256, 512, 0, stream>>>(x, w1f, ws + WS_B1P, ws + WS_GP);
    k_reduceA<<<dim3(65, 8), 256, 0, stream>>>(ws + WS_GP, ws + WS_PP, 32, 16512);
    k_reduce<<<65, 256, 0, stream>>>(ws + WS_PP, ws + WS_G, 8, 16512);
    k4_fold2<<<512, 128, 0, stream>>>(ws + WS_G, w2, b2, g2, be2, w2f, ws + WS_B2P);
    kD_main<<<256, 512, 0, stream>>>(x, w1f, ws + WS_B1P, w2f, ws + WS_B2P, ws + WS_PP);
    k5b_reduce_pool<<<dim3(66, 16), 256, 0, stream>>>(ws + WS_PP, ws + WS_PR, out);
    k6a_fc<<<dim3(16, 16), 256, 0, stream>>>(ws + WS_PR, wf, ws + WS_TP);
    k6b_final<<<1, 256, 0, stream>>>(ws + WS_TP, bf, gf, bef, out);
}

// Round 6
// 380.375 us; speedup vs baseline: 2.6964x; 2.6964x over previous
//
#include <hip/hip_runtime.h>
#include <hip/hip_bf16.h>

// FCGF point attention head — MFMA (bf16) implementation.
// x [N=524288, C=32] -> h = relu(BN(x@w1^T+b1)) [N,128]
//                    -> att = relu(BN(h@w2^T+b2)) [N,512]
// per-segment (L=32768, B=16): pooled[b] = att_b^T @ x_b / L ; gp[b] = sum att
// res = L2norm_rows(BN_over_B(pooled.flat @ wf^T + bf))
// outputs concat: res (4096) | gp (8192) | lengths (16)
//
// BN stats via moment trick: var(w.v) = w E[vv^T] w^T - (w E[v])^2 using
// S1 = x^T x (f32) and G = h^T h (bf16 MFMA). G symmetric ->
// q_k = w2[k] G w2[k]^T parallelizes as one block per channel.
// R4: bias-in-MFMA-accumulator, register prefetch of next chunk's x,
//     kB hT race fix (barrier), two-stage partial reduces.
// R5: REVERT launch_bounds (512,4)->(512,2). (512,4) capped VGPR at 64 ->
//     catastrophic spill (FETCH 1.7GB, kD 780us). 116 VGPR needs 2 blocks/CU.

#define SEGLEN 32768
#define BN_EPS 1e-5f
#define INV_N (1.0f/524288.0f)
#define INV_L (1.0f/32768.0f)

// ---- ws layout (float units) ----
#define WS_S1P   0                       // 512*1056
#define WS_S1    540672                  // 1056
#define WS_W1F   541728                  // 2048 f = 4096 bf16  [128][32]
#define WS_B1P   543776                  // 128
#define WS_GP    543904                  // 256*16512
#define WS_G     4770976                 // 16512
#define WS_W2F   4787488                 // 32768 f = 65536 bf16 [512][128]
#define WS_B2P   4820256                 // 512
#define WS_PP    4820768                 // 256*16896 pooled partials (+gp); also reduce tmp
#define WS_PR    9146144                 // 16*16384 pooled reduced
#define WS_TP    9408288                 // 16*16*256 fc partials
// end 9473824 floats = 37.9 MB

typedef __attribute__((ext_vector_type(8))) short bf16x8;  // 8 bf16 (4 VGPR)
typedef __attribute__((ext_vector_type(4))) float f32x4;   // C/D frag
#define MFMA(a,b,c) __builtin_amdgcn_mfma_f32_16x16x32_bf16(a,b,c,0,0,0)

__device__ __forceinline__ unsigned short f2b(float f) {
    unsigned u = __builtin_bit_cast(unsigned, f);
    return (unsigned short)((u + 0x7FFFu + ((u >> 16) & 1u)) >> 16);
}
__device__ __forceinline__ unsigned pk2(float lo, float hi) {
    return (unsigned)f2b(lo) | ((unsigned)f2b(hi) << 16);
}

// ---------------- K1: S1 = x^T x partials, sx partials (f32) ----------------
__global__ __launch_bounds__(256) void k1_stats_x(const float* __restrict__ x,
                                                  float* __restrict__ part) {
    __shared__ float xs[64 * 36];
    const int tid = threadIdx.x;
    const int blk = blockIdx.x;            // 512 blocks, 1024 pts each
    const long base = (long)blk * 1024;
    float acc0 = 0.f, acc1 = 0.f, acc2 = 0.f, acc3 = 0.f;
    float sxa = 0.f;
    const int i0 = (tid * 4) >> 5;
    const int j0 = (tid * 4) & 31;
    const int sp0 = tid >> 3, sc4 = (tid & 7) * 4;   // stage coords (2 rows/thread)
    float4 st0 = *(const float4*)&x[(base + sp0) * 32 + sc4];
    float4 st1 = *(const float4*)&x[(base + sp0 + 32) * 32 + sc4];
    for (int t0 = 0; t0 < 1024; t0 += 64) {
        __syncthreads();
        *(float4*)&xs[sp0 * 36 + sc4] = st0;
        *(float4*)&xs[(sp0 + 32) * 36 + sc4] = st1;
        if (t0 < 960) {   // prefetch next tile
            st0 = *(const float4*)&x[(base + t0 + 64 + sp0) * 32 + sc4];
            st1 = *(const float4*)&x[(base + t0 + 64 + sp0 + 32) * 32 + sc4];
        }
        __syncthreads();
        #pragma unroll 8
        for (int p = 0; p < 64; p++) {
            float xi = xs[p * 36 + i0];
            float4 xj = *(float4*)&xs[p * 36 + j0];
            acc0 += xi * xj.x; acc1 += xi * xj.y;
            acc2 += xi * xj.z; acc3 += xi * xj.w;
        }
        if (tid < 32) {
            #pragma unroll 8
            for (int p = 0; p < 64; p++) sxa += xs[p * 36 + tid];
        }
    }
    float* dst = part + (long)blk * 1056;
    *(float4*)&dst[tid * 4] = make_float4(acc0, acc1, acc2, acc3);
    if (tid < 32) dst[1024 + tid] = sxa;
}

// ---------------- two-stage partial reduce ----------------
__global__ void k_reduceA(const float* __restrict__ in, float* __restrict__ out,
                          int npp, int nentries) {
    // block (x,y): entries slice x, part-group y of size npp
    int e = blockIdx.x * 256 + threadIdx.x;
    if (e >= nentries) return;
    const float* src = in + (long)blockIdx.y * npp * nentries;
    float s = 0.f;
    #pragma unroll 8
    for (int p = 0; p < npp; p++) s += src[(long)p * nentries + e];
    out[(long)blockIdx.y * nentries + e] = s;
}

__global__ void k_reduce(const float* __restrict__ in, float* __restrict__ out,
                         int nparts, int nentries) {
    int e = blockIdx.x * 256 + threadIdx.x;
    if (e >= nentries) return;
    float s = 0.f;
    #pragma unroll 8
    for (int p = 0; p < nparts; p++) s += in[(long)p * nentries + e];
    out[e] = s;
}

// ---------------- K2: fold BN1 -> w1f (bf16) / b1p ----------------
__global__ __launch_bounds__(128) void k2_fold1(const float* __restrict__ S1,
                                                const float* __restrict__ w1,
                                                const float* __restrict__ b1,
                                                const float* __restrict__ g1,
                                                const float* __restrict__ be1,
                                                unsigned short* __restrict__ w1f,
                                                float* __restrict__ b1p) {
    __shared__ float s1[1056];
    const int k = threadIdx.x;
    for (int q = k; q < 1056; q += 128) s1[q] = S1[q];
    __syncthreads();
    float w[32];
    #pragma unroll
    for (int c = 0; c < 32; c++) w[c] = w1[k * 32 + c];
    float s = 0.f;
    #pragma unroll
    for (int c = 0; c < 32; c++) s += w[c] * s1[1024 + c];
    s *= INV_N;
    float q = 0.f;
    for (int i = 0; i < 32; i++) {
        float t = 0.f;
        #pragma unroll
        for (int j = 0; j < 32; j++) t += s1[i * 32 + j] * w[j];
        q += w[i] * t;
    }
    q *= INV_N;
    float var = q - s * s;
    float mu = s + b1[k];
    float a = g1[k] * rsqrtf(var + BN_EPS);
    #pragma unroll
    for (int c = 0; c < 32; c++) w1f[k * 32 + c] = f2b(a * w[c]);
    b1p[k] = a * (b1[k] - mu) + be1[k];
}

// ---------------- KB: h (MFMA) -> G = h^T h partials + sh ----------------
__global__ __launch_bounds__(512, 2) void kB_stats(const float* __restrict__ x,
                                                   const unsigned short* __restrict__ w1f,
                                                   const float* __restrict__ b1p,
                                                   float* __restrict__ gpart) {
    __shared__ unsigned short xsb[64 * 40];   // bf16 x tile [pt][40pad]
    __shared__ unsigned short hT[128 * 72];   // bf16 h^T [ch][72pad pts]
    __shared__ float shred[8 * 64];
    const int tid = threadIdx.x;
    const int wave = tid >> 6, lane = tid & 63;
    const int l15 = lane & 15, lg = lane >> 4;
    const int ptile = wave & 3, chalf = wave >> 2;
    const long base = (long)blockIdx.x * 2048;
    const f32x4 zero4 = {0.f, 0.f, 0.f, 0.f};
    bf16x8 wb1[4];
    f32x4 binit1[4];
    #pragma unroll
    for (int c = 0; c < 4; c++) {
        int ch = chalf * 64 + c * 16 + l15;
        wb1[c] = *(const bf16x8*)&w1f[ch * 32 + lg * 8];
        float b = b1p[ch];
        binit1[c] = (f32x4){b, b, b, b};
    }
    f32x4 gacc[8];
    #pragma unroll
    for (int t = 0; t < 8; t++) gacc[t] = zero4;
    float shacc[4] = {0.f, 0.f, 0.f, 0.f};
    const int sp = tid >> 3, sc4 = (tid & 7) * 4;
    float4 xsg = *(const float4*)&x[(base + sp) * 32 + sc4];
    for (int ck = 0; ck < 32; ck++) {
        __syncthreads();
        *(uint2*)&xsb[sp * 40 + sc4] =
            make_uint2(pk2(xsg.x, xsg.y), pk2(xsg.z, xsg.w));
        if (ck < 31)
            xsg = *(const float4*)&x[(base + (ck + 1) * 64 + sp) * 32 + sc4];
        __syncthreads();
        // h = relu(x @ w1f^T + b1p), write hT[ch][pt]
        bf16x8 xa = *(const bf16x8*)&xsb[(ptile * 16 + l15) * 40 + lg * 8];
        #pragma unroll
        for (int c = 0; c < 4; c++) {
            f32x4 hf = MFMA(xa, wb1[c], binit1[c]);
            float v0 = fmaxf(hf[0], 0.f);
            float v1 = fmaxf(hf[1], 0.f);
            float v2 = fmaxf(hf[2], 0.f);
            float v3 = fmaxf(hf[3], 0.f);
            shacc[c] += v0 + v1 + v2 + v3;
            int ch = chalf * 64 + c * 16 + l15;
            *(uint2*)&hT[ch * 72 + ptile * 16 + lg * 4] =
                make_uint2(pk2(v0, v1), pk2(v2, v3));
        }
        __syncthreads();   // hT ready across waves (race fix)
        // G += hT-tile outer product (wave owns row-tile `wave`)
        #pragma unroll
        for (int ks = 0; ks < 2; ks++) {
            bf16x8 ga = *(const bf16x8*)&hT[(wave * 16 + l15) * 72 + ks * 32 + lg * 8];
            #pragma unroll
            for (int ct = 0; ct < 8; ct++) {
                bf16x8 gb = *(const bf16x8*)&hT[(ct * 16 + l15) * 72 + ks * 32 + lg * 8];
                gacc[ct] = MFMA(ga, gb, gacc[ct]);
            }
        }
    }
    float* dst = gpart + (long)blockIdx.x * 16512;
    #pragma unroll
    for (int ct = 0; ct < 8; ct++) {
        #pragma unroll
        for (int r = 0; r < 4; r++)
            dst[(wave * 16 + lg * 4 + r) * 128 + ct * 16 + l15] = gacc[ct][r];
    }
    #pragma unroll
    for (int c = 0; c < 4; c++) {
        float v = shacc[c];
        v += __shfl_xor(v, 16);
        v += __shfl_xor(v, 32);
        if (lane < 16) shred[wave * 64 + c * 16 + lane] = v;
    }
    __syncthreads();
    if (tid < 128) {
        float s = 0.f;
        #pragma unroll
        for (int pt = 0; pt < 4; pt++)
            s += shred[((tid >> 6) * 4 + pt) * 64 + (tid & 63)];
        dst[16384 + tid] = s;
    }
}

// ---------------- K4: fold BN2 -> w2f (bf16 [512][128]) / b2p ----------------
__global__ __launch_bounds__(128) void k4_fold2(const float* __restrict__ G,
                                                const float* __restrict__ w2,
                                                const float* __restrict__ b2,
                                                const float* __restrict__ g2,
                                                const float* __restrict__ be2,
                                                unsigned short* __restrict__ w2f,
                                                float* __restrict__ b2p) {
    __shared__ float wsh[128];
    __shared__ float red[4];
    const int i = threadIdx.x;
    const int k = blockIdx.x;              // 512 blocks
    const float wi = w2[(long)k * 128 + i];
    wsh[i] = wi;
    __syncthreads();
    float t = 0.f;
    const float* grow = &G[i * 128];
    #pragma unroll 16
    for (int j = 0; j < 128; j++) t += grow[j] * wsh[j];
    float qp = wi * t;                     // partial of w^T G w
    float sp = wi * G[16384 + i];          // partial of w . sh
    #pragma unroll
    for (int o = 1; o < 64; o <<= 1) {
        qp += __shfl_xor(qp, o);
        sp += __shfl_xor(sp, o);
    }
    if ((i & 63) == 0) {
        red[(i >> 6) * 2 + 0] = qp;
        red[(i >> 6) * 2 + 1] = sp;
    }
    __syncthreads();
    const float q = (red[0] + red[2]) * INV_N;
    const float s = (red[1] + red[3]) * INV_N;
    const float var = q - s * s;
    const float a = g2[k] * rsqrtf(var + BN_EPS);
    w2f[(long)k * 128 + i] = f2b(a * wi);
    if (i == 0) b2p[k] = -a * s + be2[k];
}

// ---------------- KD: main fused pass (all-MFMA) ----------------
__global__ __launch_bounds__(512, 2) void kD_main(const float* __restrict__ x,
        const unsigned short* __restrict__ w1f, const float* __restrict__ b1p,
        const unsigned short* __restrict__ w2f, const float* __restrict__ b2p,
        float* __restrict__ ppart) {
    __shared__ unsigned short xT[32 * 72];      // bf16 x^T [c][72pad pts]
    __shared__ unsigned short hs[64 * 136];     // bf16 h [pt][136pad ch]
    __shared__ unsigned short attT[8][64 * 40]; // per-wave att^T [chL][40pad pts(32)]
    const int tid = threadIdx.x;
    const int wave = tid >> 6, lane = tid & 63;
    const int l15 = lane & 15, lg = lane >> 4;
    const int ptile = wave & 3, chalf = wave >> 2;
    const int kb = wave * 64;                   // att channel block
    const long base = (long)blockIdx.x * 2048;
    const f32x4 zero4 = {0.f, 0.f, 0.f, 0.f};
    bf16x8 wb1[4];
    f32x4 binit1[4];
    #pragma unroll
    for (int c = 0; c < 4; c++) {
        int ch = chalf * 64 + c * 16 + l15;
        wb1[c] = *(const bf16x8*)&w1f[ch * 32 + lg * 8];
        float b = b1p[ch];
        binit1[c] = (f32x4){b, b, b, b};
    }
    bf16x8 wb2[4][4];
    f32x4 binit2[4];
    #pragma unroll
    for (int c = 0; c < 4; c++) {
        int ch = kb + c * 16 + l15;
        #pragma unroll
        for (int ks = 0; ks < 4; ks++)
            wb2[c][ks] = *(const bf16x8*)&w2f[(long)ch * 128 + ks * 32 + lg * 8];
        float b = b2p[ch];
        binit2[c] = (f32x4){b, b, b, b};
    }
    f32x4 pacc[4][2];
    #pragma unroll
    for (int t = 0; t < 4; t++) { pacc[t][0] = zero4; pacc[t][1] = zero4; }
    float gpacc[4] = {0.f, 0.f, 0.f, 0.f};
    const int sp = tid >> 3, sc4 = (tid & 7) * 4;   // xT stage coords
    const int hpt = ptile * 16 + l15;               // h A-frag point
    float4 xsg, xh0, xh1;
    xsg = *(const float4*)&x[(base + sp) * 32 + sc4];
    {
        const float* r = &x[(base + hpt) * 32 + lg * 8];
        xh0 = *(const float4*)&r[0];
        xh1 = *(const float4*)&r[4];
    }
    for (int ck = 0; ck < 32; ck++) {
        __syncthreads();
        {   // stage x^T (bf16) from prefetched regs
            xT[(sc4 + 0) * 72 + sp] = f2b(xsg.x);
            xT[(sc4 + 1) * 72 + sp] = f2b(xsg.y);
            xT[(sc4 + 2) * 72 + sp] = f2b(xsg.z);
            xT[(sc4 + 3) * 72 + sp] = f2b(xsg.w);
        }
        {   // h tiles from prefetched regs
            bf16x8 xa;
            ((unsigned*)&xa)[0] = pk2(xh0.x, xh0.y);
            ((unsigned*)&xa)[1] = pk2(xh0.z, xh0.w);
            ((unsigned*)&xa)[2] = pk2(xh1.x, xh1.y);
            ((unsigned*)&xa)[3] = pk2(xh1.z, xh1.w);
            #pragma unroll
            for (int c = 0; c < 4; c++) {
                f32x4 hf = MFMA(xa, wb1[c], binit1[c]);
                int chh = chalf * 64 + c * 16 + l15;
                #pragma unroll
                for (int r = 0; r < 4; r++)
                    hs[(ptile * 16 + lg * 4 + r) * 136 + chh] =
                        f2b(fmaxf(hf[r], 0.f));
            }
        }
        if (ck < 31) {   // prefetch next chunk
            long nb = base + (ck + 1) * 64;
            xsg = *(const float4*)&x[(nb + sp) * 32 + sc4];
            const float* r = &x[(nb + hpt) * 32 + lg * 8];
            xh0 = *(const float4*)&r[0];
            xh1 = *(const float4*)&r[4];
        }
        __syncthreads();
        #pragma unroll
        for (int ph = 0; ph < 2; ph++) {       // two 32-pt halves
            f32x4 zt[2][4];
            #pragma unroll
            for (int r = 0; r < 2; r++) {
                zt[r][0] = binit2[0]; zt[r][1] = binit2[1];
                zt[r][2] = binit2[2]; zt[r][3] = binit2[3];
            }
            #pragma unroll
            for (int ks = 0; ks < 4; ks++) {
                bf16x8 ha[2];
                #pragma unroll
                for (int r = 0; r < 2; r++)
                    ha[r] = *(const bf16x8*)&hs[(ph * 32 + r * 16 + l15) * 136 + ks * 32 + lg * 8];
                #pragma unroll
                for (int r = 0; r < 2; r++)
                    #pragma unroll
                    for (int c = 0; c < 4; c++)
                        zt[r][c] = MFMA(ha[r], wb2[c][ks], zt[r][c]);
            }
            // relu + gp + att^T bounce (per-wave LDS region, no barrier)
            #pragma unroll
            for (int r = 0; r < 2; r++) {
                #pragma unroll
                for (int c = 0; c < 4; c++) {
                    float a0 = fmaxf(zt[r][c][0], 0.f);
                    float a1 = fmaxf(zt[r][c][1], 0.f);
                    float a2 = fmaxf(zt[r][c][2], 0.f);
                    float a3 = fmaxf(zt[r][c][3], 0.f);
                    gpacc[c] += a0 + a1 + a2 + a3;
                    *(uint2*)&attT[wave][(c * 16 + l15) * 40 + r * 16 + lg * 4] =
                        make_uint2(pk2(a0, a1), pk2(a2, a3));
                }
            }
            // pooled += att^T @ x  (K = this 32-pt half)
            bf16x8 xb[2];
            #pragma unroll
            for (int u = 0; u < 2; u++)
                xb[u] = *(const bf16x8*)&xT[(u * 16 + l15) * 72 + ph * 32 + lg * 8];
            #pragma unroll
            for (int t = 0; t < 4; t++) {
                bf16x8 aa = *(const bf16x8*)&attT[wave][(t * 16 + l15) * 40 + lg * 8];
                #pragma unroll
                for (int u = 0; u < 2; u++)
                    pacc[t][u] = MFMA(aa, xb[u], pacc[t][u]);
            }
        }
    }
    float* dst = ppart + (long)blockIdx.x * 16896;
    #pragma unroll
    for (int t = 0; t < 4; t++)
        #pragma unroll
        for (int u = 0; u < 2; u++)
            #pragma unroll
            for (int r = 0; r < 4; r++)
                dst[(kb + t * 16 + lg * 4 + r) * 32 + u * 16 + l15] = pacc[t][u][r];
    #pragma unroll
    for (int c = 0; c < 4; c++) {
        float v = gpacc[c];
        v += __shfl_xor(v, 16);
        v += __shfl_xor(v, 32);
        if (lane < 16) dst[16384 + kb + c * 16 + lane] = v;
    }
}

// ---------------- K5b: reduce pooled partials, emit gp ----------------
__global__ void k5b_reduce_pool(const float* __restrict__ part,
                                float* __restrict__ pooled_red,
                                float* __restrict__ out) {
    const int seg = blockIdx.y;
    const int e = blockIdx.x * 256 + threadIdx.x;
    if (e >= 16896) return;
    float s = 0.f;
    #pragma unroll
    for (int p = 0; p < 16; p++)
        s += part[(long)(seg * 16 + p) * 16896 + e];
    if (e < 16384) pooled_red[seg * 16384 + e] = s;
    else out[4096 + seg * 512 + (e - 16384)] = s;   // gp
}

// ---------------- K6a: fc partials over k-blocks ----------------
__global__ __launch_bounds__(256) void k6a_fc(const float* __restrict__ pr,
                                              const float* __restrict__ wf,
                                              float* __restrict__ tpart) {
    const int kbk = blockIdx.x, jb = blockIdx.y;
    const int j = jb * 16 + (threadIdx.x >> 4), b = threadIdx.x & 15;
    const float4* wrow = (const float4*)&wf[(long)j * 16384 + kbk * 1024];
    const float4* prow = (const float4*)&pr[(long)b * 16384 + kbk * 1024];
    float acc = 0.f;
    #pragma unroll 8
    for (int u = 0; u < 256; u++) {
        float4 w = wrow[u], p = prow[u];
        acc += w.x * p.x + w.y * p.y + w.z * p.z + w.w * p.w;
    }
    tpart[(kbk * 16 + b) * 256 + j] = acc;
}

// ---------------- K6b: reduce fc + BN over B + L2 normalize ----------------
__global__ __launch_bounds__(256) void k6b_final(const float* __restrict__ tpart,
                                                 const float* __restrict__ bf_,
                                                 const float* __restrict__ gf,
                                                 const float* __restrict__ bef,
                                                 float* __restrict__ out) {
    __shared__ float ts[16 * 256];
    __shared__ float rs[16 * 256];
    __shared__ float nrm[16];
    const int tid = threadIdx.x;
    for (int b = 0; b < 16; b++) {
        float s = 0.f;
        #pragma unroll
        for (int kbk = 0; kbk < 16; kbk++) s += tpart[(kbk * 16 + b) * 256 + tid];
        ts[b * 256 + tid] = s * INV_L + bf_[tid];
    }
    __syncthreads();
    float mu = 0.f;
    #pragma unroll
    for (int b = 0; b < 16; b++) mu += ts[b * 256 + tid];
    mu *= (1.f / 16.f);
    float var = 0.f;
    #pragma unroll
    for (int b = 0; b < 16; b++) {
        float d = ts[b * 256 + tid] - mu;
        var += d * d;
    }
    var *= (1.f / 16.f);
    float a = gf[tid] * rsqrtf(var + BN_EPS);
    #pragma unroll
    for (int b = 0; b < 16; b++)
        rs[b * 256 + tid] = (ts[b * 256 + tid] - mu) * a + bef[tid];
    __syncthreads();
    {   // parallel L2-norm: 16 lanes per segment
        const int pb = tid >> 4, l16 = tid & 15;
        float s = 0.f;
        #pragma unroll
        for (int j = 0; j < 16; j++) {
            float v = rs[pb * 256 + l16 + j * 16];
            s += v * v;
        }
        s += __shfl_xor(s, 1); s += __shfl_xor(s, 2);
        s += __shfl_xor(s, 4); s += __shfl_xor(s, 8);
        if (l16 == 0) nrm[pb] = fmaxf(sqrtf(s), 1e-12f);
    }
    __syncthreads();
    #pragma unroll
    for (int b = 0; b < 16; b++)
        out[b * 256 + tid] = rs[b * 256 + tid] / nrm[b];
    if (tid < 16) out[12288 + tid] = 32768.0f;   // lengths
}

extern "C" void kernel_launch(void* const* d_in, const int* in_sizes, int n_in,
                              void* d_out, int out_size, void* d_ws, size_t ws_size,
                              hipStream_t stream) {
    (void)in_sizes; (void)n_in; (void)out_size; (void)ws_size;
    const float* x   = (const float*)d_in[0];
    const float* w1  = (const float*)d_in[1];
    const float* b1  = (const float*)d_in[2];
    const float* g1  = (const float*)d_in[3];
    const float* be1 = (const float*)d_in[4];
    const float* w2  = (const float*)d_in[5];
    const float* b2  = (const float*)d_in[6];
    const float* g2  = (const float*)d_in[7];
    const float* be2 = (const float*)d_in[8];
    const float* wf  = (const float*)d_in[9];
    const float* bf  = (const float*)d_in[10];
    const float* gf  = (const float*)d_in[11];
    const float* bef = (const float*)d_in[12];
    float* out = (float*)d_out;
    float* ws = (float*)d_ws;
    unsigned short* w1f = (unsigned short*)(ws + WS_W1F);
    unsigned short* w2f = (unsigned short*)(ws + WS_W2F);

    k1_stats_x<<<512, 256, 0, stream>>>(x, ws + WS_S1P);
    k_reduceA<<<dim3(5, 8), 256, 0, stream>>>(ws + WS_S1P, ws + WS_PP, 64, 1056);
    k_reduce<<<5, 256, 0, stream>>>(ws + WS_PP, ws + WS_S1, 8, 1056);
    k2_fold1<<<1, 128, 0, stream>>>(ws + WS_S1, w1, b1, g1, be1, w1f, ws + WS_B1P);
    kB_stats<<<256, 512, 0, stream>>>(x, w1f, ws + WS_B1P, ws + WS_GP);
    k_reduceA<<<dim3(65, 8), 256, 0, stream>>>(ws + WS_GP, ws + WS_PP, 32, 16512);
    k_reduce<<<65, 256, 0, stream>>>(ws + WS_PP, ws + WS_G, 8, 16512);
    k4_fold2<<<512, 128, 0, stream>>>(ws + WS_G, w2, b2, g2, be2, w2f, ws + WS_B2P);
    kD_main<<<256, 512, 0, stream>>>(x, w1f, ws + WS_B1P, w2f, ws + WS_B2P, ws + WS_PP);
    k5b_reduce_pool<<<dim3(66, 16), 256, 0, stream>>>(ws + WS_PP, ws + WS_PR, out);
    k6a_fc<<<dim3(16, 16), 256, 0, stream>>>(ws + WS_PR, wf, ws + WS_TP);
    k6b_final<<<1, 256, 0, stream>>>(ws + WS_TP, bf, gf, bef, out);
}

// Round 7
// 360.355 us; speedup vs baseline: 2.8462x; 1.0556x over previous
//
#include <hip/hip_runtime.h>
#include <hip/hip_bf16.h>

// FCGF point attention head — MFMA (bf16) implementation.
// x [N=524288, C=32] -> h = relu(BN(x@w1^T+b1)) [N,128]
//                    -> att = relu(BN(h@w2^T+b2)) [N,512]
// per-segment (L=32768, B=16): pooled[b] = att_b^T @ x_b / L ; gp[b] = sum att
// res = L2norm_rows(BN_over_B(pooled.flat @ wf^T + bf))
// outputs concat: res (4096) | gp (8192) | lengths (16)
//
// BN stats via moment trick: var(w.v) = w E[vv^T] w^T - (w E[v])^2 using
// S1 = x^T x (f32) and G = h^T h (bf16 MFMA).
// R4: bias-in-MFMA-acc, x register prefetch, kB race-fix barrier, 2-stage reduces.
// R5: launch_bounds (512,2) — (512,4) capped VGPR at 64 -> 1.7GB spill.
// R6: v_cvt_pk_bf16_f32 (inline asm) replaces integer-emulated f32->bf16 in
//     kB/kD hot loops (~half the VALU ops; VALUBusy was 49% vs MfmaUtil 30%).

#define SEGLEN 32768
#define BN_EPS 1e-5f
#define INV_N (1.0f/524288.0f)
#define INV_L (1.0f/32768.0f)

// ---- ws layout (float units) ----
#define WS_S1P   0                       // 512*1056
#define WS_S1    540672                  // 1056
#define WS_W1F   541728                  // 2048 f = 4096 bf16  [128][32]
#define WS_B1P   543776                  // 128
#define WS_GP    543904                  // 256*16512
#define WS_G     4770976                 // 16512
#define WS_W2F   4787488                 // 32768 f = 65536 bf16 [512][128]
#define WS_B2P   4820256                 // 512
#define WS_PP    4820768                 // 256*16896 pooled partials (+gp); also reduce tmp
#define WS_PR    9146144                 // 16*16384 pooled reduced
#define WS_TP    9408288                 // 16*16*256 fc partials
// end 9473824 floats = 37.9 MB

typedef __attribute__((ext_vector_type(8))) short bf16x8;  // 8 bf16 (4 VGPR)
typedef __attribute__((ext_vector_type(4))) float f32x4;   // C/D frag
#define MFMA(a,b,c) __builtin_amdgcn_mfma_f32_16x16x32_bf16(a,b,c,0,0,0)

__device__ __forceinline__ unsigned short f2b(float f) {
    unsigned u = __builtin_bit_cast(unsigned, f);
    return (unsigned short)((u + 0x7FFFu + ((u >> 16) & 1u)) >> 16);
}
__device__ __forceinline__ unsigned pk2(float lo, float hi) {
    return (unsigned)f2b(lo) | ((unsigned)f2b(hi) << 16);
}
// HW packed convert: dst = {lo16=bf16(a), hi16=bf16(b)} — 1 VALU op for 2 values.
__device__ __forceinline__ unsigned cvtpk(float a, float b) {
    unsigned r;
    asm("v_cvt_pk_bf16_f32 %0, %1, %2" : "=v"(r) : "v"(a), "v"(b));
    return r;
}

// ---------------- K1: S1 = x^T x partials, sx partials (f32) ----------------
__global__ __launch_bounds__(256) void k1_stats_x(const float* __restrict__ x,
                                                  float* __restrict__ part) {
    __shared__ float xs[64 * 36];
    const int tid = threadIdx.x;
    const int blk = blockIdx.x;            // 512 blocks, 1024 pts each
    const long base = (long)blk * 1024;
    float acc0 = 0.f, acc1 = 0.f, acc2 = 0.f, acc3 = 0.f;
    float sxa = 0.f;
    const int i0 = (tid * 4) >> 5;
    const int j0 = (tid * 4) & 31;
    const int sp0 = tid >> 3, sc4 = (tid & 7) * 4;   // stage coords (2 rows/thread)
    float4 st0 = *(const float4*)&x[(base + sp0) * 32 + sc4];
    float4 st1 = *(const float4*)&x[(base + sp0 + 32) * 32 + sc4];
    for (int t0 = 0; t0 < 1024; t0 += 64) {
        __syncthreads();
        *(float4*)&xs[sp0 * 36 + sc4] = st0;
        *(float4*)&xs[(sp0 + 32) * 36 + sc4] = st1;
        if (t0 < 960) {   // prefetch next tile
            st0 = *(const float4*)&x[(base + t0 + 64 + sp0) * 32 + sc4];
            st1 = *(const float4*)&x[(base + t0 + 64 + sp0 + 32) * 32 + sc4];
        }
        __syncthreads();
        #pragma unroll 8
        for (int p = 0; p < 64; p++) {
            float xi = xs[p * 36 + i0];
            float4 xj = *(float4*)&xs[p * 36 + j0];
            acc0 += xi * xj.x; acc1 += xi * xj.y;
            acc2 += xi * xj.z; acc3 += xi * xj.w;
        }
        if (tid < 32) {
            #pragma unroll 8
            for (int p = 0; p < 64; p++) sxa += xs[p * 36 + tid];
        }
    }
    float* dst = part + (long)blk * 1056;
    *(float4*)&dst[tid * 4] = make_float4(acc0, acc1, acc2, acc3);
    if (tid < 32) dst[1024 + tid] = sxa;
}

// ---------------- two-stage partial reduce ----------------
__global__ void k_reduceA(const float* __restrict__ in, float* __restrict__ out,
                          int npp, int nentries) {
    int e = blockIdx.x * 256 + threadIdx.x;
    if (e >= nentries) return;
    const float* src = in + (long)blockIdx.y * npp * nentries;
    float s = 0.f;
    #pragma unroll 8
    for (int p = 0; p < npp; p++) s += src[(long)p * nentries + e];
    out[(long)blockIdx.y * nentries + e] = s;
}

__global__ void k_reduce(const float* __restrict__ in, float* __restrict__ out,
                         int nparts, int nentries) {
    int e = blockIdx.x * 256 + threadIdx.x;
    if (e >= nentries) return;
    float s = 0.f;
    #pragma unroll 8
    for (int p = 0; p < nparts; p++) s += in[(long)p * nentries + e];
    out[e] = s;
}

// ---------------- K2: fold BN1 -> w1f (bf16) / b1p ----------------
__global__ __launch_bounds__(128) void k2_fold1(const float* __restrict__ S1,
                                                const float* __restrict__ w1,
                                                const float* __restrict__ b1,
                                                const float* __restrict__ g1,
                                                const float* __restrict__ be1,
                                                unsigned short* __restrict__ w1f,
                                                float* __restrict__ b1p) {
    __shared__ float s1[1056];
    const int k = threadIdx.x;
    for (int q = k; q < 1056; q += 128) s1[q] = S1[q];
    __syncthreads();
    float w[32];
    #pragma unroll
    for (int c = 0; c < 32; c++) w[c] = w1[k * 32 + c];
    float s = 0.f;
    #pragma unroll
    for (int c = 0; c < 32; c++) s += w[c] * s1[1024 + c];
    s *= INV_N;
    float q = 0.f;
    for (int i = 0; i < 32; i++) {
        float t = 0.f;
        #pragma unroll
        for (int j = 0; j < 32; j++) t += s1[i * 32 + j] * w[j];
        q += w[i] * t;
    }
    q *= INV_N;
    float var = q - s * s;
    float mu = s + b1[k];
    float a = g1[k] * rsqrtf(var + BN_EPS);
    #pragma unroll
    for (int c = 0; c < 32; c++) w1f[k * 32 + c] = f2b(a * w[c]);
    b1p[k] = a * (b1[k] - mu) + be1[k];
}

// ---------------- KB: h (MFMA) -> G = h^T h partials + sh ----------------
__global__ __launch_bounds__(512, 2) void kB_stats(const float* __restrict__ x,
                                                   const unsigned short* __restrict__ w1f,
                                                   const float* __restrict__ b1p,
                                                   float* __restrict__ gpart) {
    __shared__ unsigned short xsb[64 * 40];   // bf16 x tile [pt][40pad]
    __shared__ unsigned short hT[128 * 72];   // bf16 h^T [ch][72pad pts]
    __shared__ float shred[8 * 64];
    const int tid = threadIdx.x;
    const int wave = tid >> 6, lane = tid & 63;
    const int l15 = lane & 15, lg = lane >> 4;
    const int ptile = wave & 3, chalf = wave >> 2;
    const long base = (long)blockIdx.x * 2048;
    const f32x4 zero4 = {0.f, 0.f, 0.f, 0.f};
    bf16x8 wb1[4];
    f32x4 binit1[4];
    #pragma unroll
    for (int c = 0; c < 4; c++) {
        int ch = chalf * 64 + c * 16 + l15;
        wb1[c] = *(const bf16x8*)&w1f[ch * 32 + lg * 8];
        float b = b1p[ch];
        binit1[c] = (f32x4){b, b, b, b};
    }
    f32x4 gacc[8];
    #pragma unroll
    for (int t = 0; t < 8; t++) gacc[t] = zero4;
    float shacc[4] = {0.f, 0.f, 0.f, 0.f};
    const int sp = tid >> 3, sc4 = (tid & 7) * 4;
    float4 xsg = *(const float4*)&x[(base + sp) * 32 + sc4];
    for (int ck = 0; ck < 32; ck++) {
        __syncthreads();
        *(uint2*)&xsb[sp * 40 + sc4] =
            make_uint2(cvtpk(xsg.x, xsg.y), cvtpk(xsg.z, xsg.w));
        if (ck < 31)
            xsg = *(const float4*)&x[(base + (ck + 1) * 64 + sp) * 32 + sc4];
        __syncthreads();
        // h = relu(x @ w1f^T + b1p), write hT[ch][pt]
        bf16x8 xa = *(const bf16x8*)&xsb[(ptile * 16 + l15) * 40 + lg * 8];
        #pragma unroll
        for (int c = 0; c < 4; c++) {
            f32x4 hf = MFMA(xa, wb1[c], binit1[c]);
            float v0 = fmaxf(hf[0], 0.f);
            float v1 = fmaxf(hf[1], 0.f);
            float v2 = fmaxf(hf[2], 0.f);
            float v3 = fmaxf(hf[3], 0.f);
            shacc[c] += (v0 + v1) + (v2 + v3);
            int ch = chalf * 64 + c * 16 + l15;
            *(uint2*)&hT[ch * 72 + ptile * 16 + lg * 4] =
                make_uint2(cvtpk(v0, v1), cvtpk(v2, v3));
        }
        __syncthreads();   // hT ready across waves (race fix)
        // G += hT-tile outer product (wave owns row-tile `wave`)
        #pragma unroll
        for (int ks = 0; ks < 2; ks++) {
            bf16x8 ga = *(const bf16x8*)&hT[(wave * 16 + l15) * 72 + ks * 32 + lg * 8];
            #pragma unroll
            for (int ct = 0; ct < 8; ct++) {
                bf16x8 gb = *(const bf16x8*)&hT[(ct * 16 + l15) * 72 + ks * 32 + lg * 8];
                gacc[ct] = MFMA(ga, gb, gacc[ct]);
            }
        }
    }
    float* dst = gpart + (long)blockIdx.x * 16512;
    #pragma unroll
    for (int ct = 0; ct < 8; ct++) {
        #pragma unroll
        for (int r = 0; r < 4; r++)
            dst[(wave * 16 + lg * 4 + r) * 128 + ct * 16 + l15] = gacc[ct][r];
    }
    #pragma unroll
    for (int c = 0; c < 4; c++) {
        float v = shacc[c];
        v += __shfl_xor(v, 16);
        v += __shfl_xor(v, 32);
        if (lane < 16) shred[wave * 64 + c * 16 + lane] = v;
    }
    __syncthreads();
    if (tid < 128) {
        float s = 0.f;
        #pragma unroll
        for (int pt = 0; pt < 4; pt++)
            s += shred[((tid >> 6) * 4 + pt) * 64 + (tid & 63)];
        dst[16384 + tid] = s;
    }
}

// ---------------- K4: fold BN2 -> w2f (bf16 [512][128]) / b2p ----------------
__global__ __launch_bounds__(128) void k4_fold2(const float* __restrict__ G,
                                                const float* __restrict__ w2,
                                                const float* __restrict__ b2,
                                                const float* __restrict__ g2,
                                                const float* __restrict__ be2,
                                                unsigned short* __restrict__ w2f,
                                                float* __restrict__ b2p) {
    __shared__ float wsh[128];
    __shared__ float red[4];
    const int i = threadIdx.x;
    const int k = blockIdx.x;              // 512 blocks
    const float wi = w2[(long)k * 128 + i];
    wsh[i] = wi;
    __syncthreads();
    float t = 0.f;
    const float* grow = &G[i * 128];
    #pragma unroll 16
    for (int j = 0; j < 128; j++) t += grow[j] * wsh[j];
    float qp = wi * t;                     // partial of w^T G w
    float sp = wi * G[16384 + i];          // partial of w . sh
    #pragma unroll
    for (int o = 1; o < 64; o <<= 1) {
        qp += __shfl_xor(qp, o);
        sp += __shfl_xor(sp, o);
    }
    if ((i & 63) == 0) {
        red[(i >> 6) * 2 + 0] = qp;
        red[(i >> 6) * 2 + 1] = sp;
    }
    __syncthreads();
    const float q = (red[0] + red[2]) * INV_N;
    const float s = (red[1] + red[3]) * INV_N;
    const float var = q - s * s;
    const float a = g2[k] * rsqrtf(var + BN_EPS);
    w2f[(long)k * 128 + i] = f2b(a * wi);
    if (i == 0) b2p[k] = -a * s + be2[k];
}

// ---------------- KD: main fused pass (all-MFMA) ----------------
__global__ __launch_bounds__(512, 2) void kD_main(const float* __restrict__ x,
        const unsigned short* __restrict__ w1f, const float* __restrict__ b1p,
        const unsigned short* __restrict__ w2f, const float* __restrict__ b2p,
        float* __restrict__ ppart) {
    __shared__ unsigned short xT[32 * 72];      // bf16 x^T [c][72pad pts]
    __shared__ unsigned short hs[64 * 136];     // bf16 h [pt][136pad ch]
    __shared__ unsigned short attT[8][64 * 40]; // per-wave att^T [chL][40pad pts(32)]
    const int tid = threadIdx.x;
    const int wave = tid >> 6, lane = tid & 63;
    const int l15 = lane & 15, lg = lane >> 4;
    const int ptile = wave & 3, chalf = wave >> 2;
    const int kb = wave * 64;                   // att channel block
    const long base = (long)blockIdx.x * 2048;
    const f32x4 zero4 = {0.f, 0.f, 0.f, 0.f};
    bf16x8 wb1[4];
    f32x4 binit1[4];
    #pragma unroll
    for (int c = 0; c < 4; c++) {
        int ch = chalf * 64 + c * 16 + l15;
        wb1[c] = *(const bf16x8*)&w1f[ch * 32 + lg * 8];
        float b = b1p[ch];
        binit1[c] = (f32x4){b, b, b, b};
    }
    bf16x8 wb2[4][4];
    f32x4 binit2[4];
    #pragma unroll
    for (int c = 0; c < 4; c++) {
        int ch = kb + c * 16 + l15;
        #pragma unroll
        for (int ks = 0; ks < 4; ks++)
            wb2[c][ks] = *(const bf16x8*)&w2f[(long)ch * 128 + ks * 32 + lg * 8];
        float b = b2p[ch];
        binit2[c] = (f32x4){b, b, b, b};
    }
    f32x4 pacc[4][2];
    #pragma unroll
    for (int t = 0; t < 4; t++) { pacc[t][0] = zero4; pacc[t][1] = zero4; }
    float gpacc[4] = {0.f, 0.f, 0.f, 0.f};
    const int sp = tid >> 3, sc4 = (tid & 7) * 4;   // xT stage coords
    const int hpt = ptile * 16 + l15;               // h A-frag point
    float4 xsg, xh0, xh1;
    xsg = *(const float4*)&x[(base + sp) * 32 + sc4];
    {
        const float* r = &x[(base + hpt) * 32 + lg * 8];
        xh0 = *(const float4*)&r[0];
        xh1 = *(const float4*)&r[4];
    }
    for (int ck = 0; ck < 32; ck++) {
        __syncthreads();
        {   // stage x^T (bf16) from prefetched regs (2 cvt_pk + hi extracts)
            unsigned dxy = cvtpk(xsg.x, xsg.y);
            unsigned dzw = cvtpk(xsg.z, xsg.w);
            xT[(sc4 + 0) * 72 + sp] = (unsigned short)dxy;
            xT[(sc4 + 1) * 72 + sp] = (unsigned short)(dxy >> 16);
            xT[(sc4 + 2) * 72 + sp] = (unsigned short)dzw;
            xT[(sc4 + 3) * 72 + sp] = (unsigned short)(dzw >> 16);
        }
        {   // h tiles from prefetched regs
            bf16x8 xa;
            ((unsigned*)&xa)[0] = cvtpk(xh0.x, xh0.y);
            ((unsigned*)&xa)[1] = cvtpk(xh0.z, xh0.w);
            ((unsigned*)&xa)[2] = cvtpk(xh1.x, xh1.y);
            ((unsigned*)&xa)[3] = cvtpk(xh1.z, xh1.w);
            #pragma unroll
            for (int c = 0; c < 4; c++) {
                f32x4 hf = MFMA(xa, wb1[c], binit1[c]);
                int chh = chalf * 64 + c * 16 + l15;
                int rb = ptile * 16 + lg * 4;
                unsigned d0 = cvtpk(fmaxf(hf[0], 0.f), fmaxf(hf[1], 0.f));
                unsigned d1 = cvtpk(fmaxf(hf[2], 0.f), fmaxf(hf[3], 0.f));
                hs[(rb + 0) * 136 + chh] = (unsigned short)d0;
                hs[(rb + 1) * 136 + chh] = (unsigned short)(d0 >> 16);
                hs[(rb + 2) * 136 + chh] = (unsigned short)d1;
                hs[(rb + 3) * 136 + chh] = (unsigned short)(d1 >> 16);
            }
        }
        if (ck < 31) {   // prefetch next chunk
            long nb = base + (ck + 1) * 64;
            xsg = *(const float4*)&x[(nb + sp) * 32 + sc4];
            const float* r = &x[(nb + hpt) * 32 + lg * 8];
            xh0 = *(const float4*)&r[0];
            xh1 = *(const float4*)&r[4];
        }
        __syncthreads();
        #pragma unroll
        for (int ph = 0; ph < 2; ph++) {       // two 32-pt halves
            f32x4 zt[2][4];
            #pragma unroll
            for (int r = 0; r < 2; r++) {
                zt[r][0] = binit2[0]; zt[r][1] = binit2[1];
                zt[r][2] = binit2[2]; zt[r][3] = binit2[3];
            }
            #pragma unroll
            for (int ks = 0; ks < 4; ks++) {
                bf16x8 ha[2];
                #pragma unroll
                for (int r = 0; r < 2; r++)
                    ha[r] = *(const bf16x8*)&hs[(ph * 32 + r * 16 + l15) * 136 + ks * 32 + lg * 8];
                #pragma unroll
                for (int r = 0; r < 2; r++)
                    #pragma unroll
                    for (int c = 0; c < 4; c++)
                        zt[r][c] = MFMA(ha[r], wb2[c][ks], zt[r][c]);
            }
            // relu + gp + att^T bounce (per-wave LDS region, no barrier)
            #pragma unroll
            for (int r = 0; r < 2; r++) {
                #pragma unroll
                for (int c = 0; c < 4; c++) {
                    float a0 = fmaxf(zt[r][c][0], 0.f);
                    float a1 = fmaxf(zt[r][c][1], 0.f);
                    float a2 = fmaxf(zt[r][c][2], 0.f);
                    float a3 = fmaxf(zt[r][c][3], 0.f);
                    gpacc[c] += (a0 + a1) + (a2 + a3);
                    *(uint2*)&attT[wave][(c * 16 + l15) * 40 + r * 16 + lg * 4] =
                        make_uint2(cvtpk(a0, a1), cvtpk(a2, a3));
                }
            }
            // pooled += att^T @ x  (K = this 32-pt half)
            bf16x8 xb[2];
            #pragma unroll
            for (int u = 0; u < 2; u++)
                xb[u] = *(const bf16x8*)&xT[(u * 16 + l15) * 72 + ph * 32 + lg * 8];
            #pragma unroll
            for (int t = 0; t < 4; t++) {
                bf16x8 aa = *(const bf16x8*)&attT[wave][(t * 16 + l15) * 40 + lg * 8];
                #pragma unroll
                for (int u = 0; u < 2; u++)
                    pacc[t][u] = MFMA(aa, xb[u], pacc[t][u]);
            }
        }
    }
    float* dst = ppart + (long)blockIdx.x * 16896;
    #pragma unroll
    for (int t = 0; t < 4; t++)
        #pragma unroll
        for (int u = 0; u < 2; u++)
            #pragma unroll
            for (int r = 0; r < 4; r++)
                dst[(kb + t * 16 + lg * 4 + r) * 32 + u * 16 + l15] = pacc[t][u][r];
    #pragma unroll
    for (int c = 0; c < 4; c++) {
        float v = gpacc[c];
        v += __shfl_xor(v, 16);
        v += __shfl_xor(v, 32);
        if (lane < 16) dst[16384 + kb + c * 16 + lane] = v;
    }
}

// ---------------- K5b: reduce pooled partials, emit gp ----------------
__global__ void k5b_reduce_pool(const float* __restrict__ part,
                                float* __restrict__ pooled_red,
                                float* __restrict__ out) {
    const int seg = blockIdx.y;
    const int e = blockIdx.x * 256 + threadIdx.x;
    if (e >= 16896) return;
    float s = 0.f;
    #pragma unroll
    for (int p = 0; p < 16; p++)
        s += part[(long)(seg * 16 + p) * 16896 + e];
    if (e < 16384) pooled_red[seg * 16384 + e] = s;
    else out[4096 + seg * 512 + (e - 16384)] = s;   // gp
}

// ---------------- K6a: fc partials over k-blocks ----------------
__global__ __launch_bounds__(256) void k6a_fc(const float* __restrict__ pr,
                                              const float* __restrict__ wf,
                                              float* __restrict__ tpart) {
    const int kbk = blockIdx.x, jb = blockIdx.y;
    const int j = jb * 16 + (threadIdx.x >> 4), b = threadIdx.x & 15;
    const float4* wrow = (const float4*)&wf[(long)j * 16384 + kbk * 1024];
    const float4* prow = (const float4*)&pr[(long)b * 16384 + kbk * 1024];
    float acc = 0.f;
    #pragma unroll 8
    for (int u = 0; u < 256; u++) {
        float4 w = wrow[u], p = prow[u];
        acc += w.x * p.x + w.y * p.y + w.z * p.z + w.w * p.w;
    }
    tpart[(kbk * 16 + b) * 256 + j] = acc;
}

// ---------------- K6b: reduce fc + BN over B + L2 normalize ----------------
__global__ __launch_bounds__(256) void k6b_final(const float* __restrict__ tpart,
                                                 const float* __restrict__ bf_,
                                                 const float* __restrict__ gf,
                                                 const float* __restrict__ bef,
                                                 float* __restrict__ out) {
    __shared__ float ts[16 * 256];
    __shared__ float rs[16 * 256];
    __shared__ float nrm[16];
    const int tid = threadIdx.x;
    for (int b = 0; b < 16; b++) {
        float s = 0.f;
        #pragma unroll
        for (int kbk = 0; kbk < 16; kbk++) s += tpart[(kbk * 16 + b) * 256 + tid];
        ts[b * 256 + tid] = s * INV_L + bf_[tid];
    }
    __syncthreads();
    float mu = 0.f;
    #pragma unroll
    for (int b = 0; b < 16; b++) mu += ts[b * 256 + tid];
    mu *= (1.f / 16.f);
    float var = 0.f;
    #pragma unroll
    for (int b = 0; b < 16; b++) {
        float d = ts[b * 256 + tid] - mu;
        var += d * d;
    }
    var *= (1.f / 16.f);
    float a = gf[tid] * rsqrtf(var + BN_EPS);
    #pragma unroll
    for (int b = 0; b < 16; b++)
        rs[b * 256 + tid] = (ts[b * 256 + tid] - mu) * a + bef[tid];
    __syncthreads();
    {   // parallel L2-norm: 16 lanes per segment
        const int pb = tid >> 4, l16 = tid & 15;
        float s = 0.f;
        #pragma unroll
        for (int j = 0; j < 16; j++) {
            float v = rs[pb * 256 + l16 + j * 16];
            s += v * v;
        }
        s += __shfl_xor(s, 1); s += __shfl_xor(s, 2);
        s += __shfl_xor(s, 4); s += __shfl_xor(s, 8);
        if (l16 == 0) nrm[pb] = fmaxf(sqrtf(s), 1e-12f);
    }
    __syncthreads();
    #pragma unroll
    for (int b = 0; b < 16; b++)
        out[b * 256 + tid] = rs[b * 256 + tid] / nrm[b];
    if (tid < 16) out[12288 + tid] = 32768.0f;   // lengths
}

extern "C" void kernel_launch(void* const* d_in, const int* in_sizes, int n_in,
                              void* d_out, int out_size, void* d_ws, size_t ws_size,
                              hipStream_t stream) {
    (void)in_sizes; (void)n_in; (void)out_size; (void)ws_size;
    const float* x   = (const float*)d_in[0];
    const float* w1  = (const float*)d_in[1];
    const float* b1  = (const float*)d_in[2];
    const float* g1  = (const float*)d_in[3];
    const float* be1 = (const float*)d_in[4];
    const float* w2  = (const float*)d_in[5];
    const float* b2  = (const float*)d_in[6];
    const float* g2  = (const float*)d_in[7];
    const float* be2 = (const float*)d_in[8];
    const float* wf  = (const float*)d_in[9];
    const float* bf  = (const float*)d_in[10];
    const float* gf  = (const float*)d_in[11];
    const float* bef = (const float*)d_in[12];
    float* out = (float*)d_out;
    float* ws = (float*)d_ws;
    unsigned short* w1f = (unsigned short*)(ws + WS_W1F);
    unsigned short* w2f = (unsigned short*)(ws + WS_W2F);

    k1_stats_x<<<512, 256, 0, stream>>>(x, ws + WS_S1P);
    k_reduceA<<<dim3(5, 8), 256, 0, stream>>>(ws + WS_S1P, ws + WS_PP, 64, 1056);
    k_reduce<<<5, 256, 0, stream>>>(ws + WS_PP, ws + WS_S1, 8, 1056);
    k2_fold1<<<1, 128, 0, stream>>>(ws + WS_S1, w1, b1, g1, be1, w1f, ws + WS_B1P);
    kB_stats<<<256, 512, 0, stream>>>(x, w1f, ws + WS_B1P, ws + WS_GP);
    k_reduceA<<<dim3(65, 8), 256, 0, stream>>>(ws + WS_GP, ws + WS_PP, 32, 16512);
    k_reduce<<<65, 256, 0, stream>>>(ws + WS_PP, ws + WS_G, 8, 16512);
    k4_fold2<<<512, 128, 0, stream>>>(ws + WS_G, w2, b2, g2, be2, w2f, ws + WS_B2P);
    kD_main<<<256, 512, 0, stream>>>(x, w1f, ws + WS_B1P, w2f, ws + WS_B2P, ws + WS_PP);
    k5b_reduce_pool<<<dim3(66, 16), 256, 0, stream>>>(ws + WS_PP, ws + WS_PR, out);
    k6a_fc<<<dim3(16, 16), 256, 0, stream>>>(ws + WS_PR, wf, ws + WS_TP);
    k6b_final<<<1, 256, 0, stream>>>(ws + WS_TP, bf, gf, bef, out);
}